// Round 1
// baseline (262.146 us; speedup 1.0000x reference)
//
#include <hip/hip_runtime.h>

// MPNN (NNConv x2 + final linear) on MI355X.
// Fusion: msg = Z @ Bt  where Z[e, i*64+k] = x_j[e,i]*ea[e,k] formed on the fly,
//         Bt[(i*64+k)][o] = nn_w[k][i*64+o]  (packed transposed, f16).
// Never materializes the [E,64,64] per-edge weight tensor.

#define NNODES 10000
#define NEDGES 50000
#define CH 64
#define K4 4096
#define KTOT 4160      // 4096 + 64 bias rows
#define NSTAGES 65     // K processed in 64-wide stages (64 + 1 bias stage)

typedef _Float16 f16;
typedef f16 f16x8 __attribute__((ext_vector_type(8)));
typedef float f32x4 __attribute__((ext_vector_type(4)));

// Pack nn_w [64][4096] + nn_b [4096] into Bt [64 cols o][4160 kk] f16 (B^T layout).
// Bt[o][i*64+k] = nn_w[k][i*64+o];  Bt[o][4096+i] = nn_b[i*64+o].
__global__ void pack_b_kernel(const float* __restrict__ nn_w,
                              const float* __restrict__ nn_b,
                              f16* __restrict__ Bt) {
    int idx = blockIdx.x * 256 + threadIdx.x;
    if (idx >= CH * KTOT) return;
    int o  = idx / KTOT;
    int kk = idx - o * KTOT;
    float v;
    if (kk < K4) {
        int i = kk >> 6;
        int k = kk & 63;
        v = nn_w[k * K4 + i * CH + o];
    } else {
        int i = kk - K4;
        v = nn_b[i * CH + o];
    }
    Bt[idx] = (f16)v;
}

// out[n][o] = bias[o] + sum_k act(x[n][k]) * lw[k][o]
// One wave per node: x row reads are wave-uniform (scalar loads), lw coalesced.
template<bool RELU_IN>
__global__ void root_linear_kernel(const float* __restrict__ x,
                                   const float* __restrict__ lw,
                                   const float* __restrict__ bias,
                                   float* __restrict__ out) {
    int idx = blockIdx.x * 256 + threadIdx.x;
    if (idx >= NNODES * CH) return;
    int n = idx >> 6;
    int o = idx & 63;
    const float* xr = x + n * CH;
    float acc = bias[o];
#pragma unroll
    for (int k = 0; k < CH; ++k) {
        float xv = xr[k];
        if (RELU_IN) xv = fmaxf(xv, 0.f);
        acc = fmaf(xv, lw[k * CH + o], acc);
    }
    out[idx] = acc;
}

// Edge GEMM: per block 128 edges, 4 waves (wave = 32 edges x 64 cols).
// K = 4160 split across blockIdx.y (2 halves) for occupancy; partial sums
// land in out[] via atomicAdd (segment_sum over dst).
template<bool RELU_IN>
__global__ __launch_bounds__(256)
void edge_gemm_kernel(const float* __restrict__ x,
                      const int* __restrict__ ei,   // [2][E]: src then dst
                      const float* __restrict__ ea, // [E][64]
                      const f16* __restrict__ Bt,   // [64][4160]
                      float* __restrict__ out) {    // [N][64], atomicAdd
    __shared__ f16 xjS[64][132];   // transposed: [i][e_local]  (pad 132: 2-way = free)
    __shared__ f16 eaS[128][72];   // [e_local][k]              (pad 72:  2-way = free)
    __shared__ f16 BS[64][72];     // [col][k_local]            (pad 72:  2-way = free)

    int t  = threadIdx.x;
    int e0 = blockIdx.x * 128;

    // Gather x[src[e]] (with optional fused ReLU) and ea rows into LDS as f16.
    for (int v = 0; v < 128 * 64; v += 256) {
        int idx = v + t;
        int el = idx >> 6;
        int i  = idx & 63;
        int e  = e0 + el;
        float xv = 0.f, av = 0.f;
        if (e < NEDGES) {
            int srow = ei[e];                     // src = edge_index[0][e]
            xv = x[srow * CH + i];
            if (RELU_IN) xv = fmaxf(xv, 0.f);
            av = ea[e * CH + i];
        }
        xjS[i][el] = (f16)xv;
        eaS[el][i] = (f16)av;
    }

    f32x4 zero4 = {0.f, 0.f, 0.f, 0.f};
    f32x4 acc[2][4];
#pragma unroll
    for (int ms = 0; ms < 2; ++ms)
#pragma unroll
        for (int tn = 0; tn < 4; ++tn)
            acc[ms][tn] = zero4;

    int wv  = t >> 6;       // wave id 0..3
    int ln  = t & 63;
    int l15 = ln & 15;
    int l4  = ln >> 4;      // 0..3  (k-group)
    int er0 = wv * 32;      // wave's edge base within block

    int sb = blockIdx.y * 33;
    int se = min(NSTAGES, sb + 33);

    for (int s = sb; s < se; ++s) {
        __syncthreads();   // previous stage's BS reads done (also covers gather on 1st iter)
        {   // stage B chunk: 64 cols x 64 k  (8 KB), 2x 16B per thread
            int col = t & 63;
            int kg  = t >> 6;
            const uint4* src = (const uint4*)(Bt + col * KTOT + s * 64);
            uint4* drow = (uint4*)(&BS[col][0]);
            drow[kg]     = src[kg];
            drow[kg + 4] = src[kg + 4];
        }
        __syncthreads();

        if (s < 64) {
            // A[e][kk] = xj[e][i=s] * ea[e][k],  kk = s*64 + k
            f16 xa = xjS[s][er0 + l15];
            f16 xb = xjS[s][er0 + 16 + l15];
            f16x8 xav = {xa, xa, xa, xa, xa, xa, xa, xa};
            f16x8 xbv = {xb, xb, xb, xb, xb, xb, xb, xb};
#pragma unroll
            for (int h = 0; h < 2; ++h) {
                f16x8 eava = *(const f16x8*)&eaS[er0 + l15][h * 32 + l4 * 8];
                f16x8 eavb = *(const f16x8*)&eaS[er0 + 16 + l15][h * 32 + l4 * 8];
                f16x8 afa = eava * xav;
                f16x8 afb = eavb * xbv;
#pragma unroll
                for (int tn = 0; tn < 4; ++tn) {
                    f16x8 bf = *(const f16x8*)&BS[tn * 16 + l15][h * 32 + l4 * 8];
                    acc[0][tn] = __builtin_amdgcn_mfma_f32_16x16x32_f16(afa, bf, acc[0][tn], 0, 0, 0);
                    acc[1][tn] = __builtin_amdgcn_mfma_f32_16x16x32_f16(afb, bf, acc[1][tn], 0, 0, 0);
                }
            }
        } else {
            // bias stage: A[e][4096+i] = xj[e][i]
#pragma unroll
            for (int h = 0; h < 2; ++h) {
                f16x8 afa, afb;
#pragma unroll
                for (int j = 0; j < 8; ++j) {
                    int ii = h * 32 + l4 * 8 + j;
                    afa[j] = xjS[ii][er0 + l15];
                    afb[j] = xjS[ii][er0 + 16 + l15];
                }
#pragma unroll
                for (int tn = 0; tn < 4; ++tn) {
                    f16x8 bf = *(const f16x8*)&BS[tn * 16 + l15][h * 32 + l4 * 8];
                    acc[0][tn] = __builtin_amdgcn_mfma_f32_16x16x32_f16(afa, bf, acc[0][tn], 0, 0, 0);
                    acc[1][tn] = __builtin_amdgcn_mfma_f32_16x16x32_f16(afb, bf, acc[1][tn], 0, 0, 0);
                }
            }
        }
    }

    // Scatter: D lane map (verified m89): col = lane&15, row = (lane>>4)*4 + reg.
#pragma unroll
    for (int ms = 0; ms < 2; ++ms) {
#pragma unroll
        for (int q = 0; q < 4; ++q) {
            int el = er0 + ms * 16 + l4 * 4 + q;
            int e  = e0 + el;
            if (e < NEDGES) {
                int drow = ei[NEDGES + e];        // dst = edge_index[1][e]
                float* orow = out + drow * CH;
#pragma unroll
                for (int tn = 0; tn < 4; ++tn) {
                    atomicAdd(orow + tn * 16 + l15, acc[ms][tn][q]);
                }
            }
        }
    }
}

extern "C" void kernel_launch(void* const* d_in, const int* in_sizes, int n_in,
                              void* d_out, int out_size, void* d_ws, size_t ws_size,
                              hipStream_t stream) {
    const float* feature = (const float*)d_in[0];
    const int*   ei      = (const int*)d_in[1];
    const float* ea      = (const float*)d_in[2];
    const float* nn_w0   = (const float*)d_in[3];
    const float* nn_b0   = (const float*)d_in[4];
    const float* lin_w0  = (const float*)d_in[5];
    const float* bias0   = (const float*)d_in[6];
    const float* nn_w1   = (const float*)d_in[7];
    const float* nn_b1   = (const float*)d_in[8];
    const float* lin_w1  = (const float*)d_in[9];
    const float* bias1   = (const float*)d_in[10];
    const float* fin_w   = (const float*)d_in[11];
    const float* fin_b   = (const float*)d_in[12];
    float* out = (float*)d_out;

    char* ws = (char*)d_ws;
    float* buf0 = (float*)ws;                        // 2,560,000 B
    float* buf1 = (float*)(ws + 2560000);            // 2,560,000 B
    f16* Bt0 = (f16*)(ws + 5120000);                 // 532,480 B
    f16* Bt1 = (f16*)(ws + 5120000 + 532480);        // 532,480 B

    int pack_blocks = (CH * KTOT + 255) / 256;
    pack_b_kernel<<<pack_blocks, 256, 0, stream>>>(nn_w0, nn_b0, Bt0);
    pack_b_kernel<<<pack_blocks, 256, 0, stream>>>(nn_w1, nn_b1, Bt1);

    dim3 rg((NNODES * CH + 255) / 256);
    dim3 eg((NEDGES + 127) / 128, 2);

    // layer 0
    root_linear_kernel<false><<<rg, 256, 0, stream>>>(feature, lin_w0, bias0, buf0);
    edge_gemm_kernel<false><<<eg, 256, 0, stream>>>(feature, ei, ea, Bt0, buf0);
    // layer 1 (ReLU fused into loads)
    root_linear_kernel<true><<<rg, 256, 0, stream>>>(buf0, lin_w1, bias1, buf1);
    edge_gemm_kernel<true><<<eg, 256, 0, stream>>>(buf0, ei, ea, Bt1, buf1);
    // final linear (ReLU fused)
    root_linear_kernel<true><<<rg, 256, 0, stream>>>(buf1, fin_w, fin_b, out);
}

// Round 2
// 204.024 us; speedup vs baseline: 1.2849x; 1.2849x over previous
//
#include <hip/hip_runtime.h>

// MPNN (NNConv x2 + final linear) on MI355X.
// msg = Z @ B where Z[e, i*64+k] = x_j[e,i]*ea[e,k] formed on the fly in regs.
// B is pre-swizzled into MFMA-fragment-major layout so every B access is a
// fully-coalesced 1KB/wave global load into registers: NO barriers in K-loop.

#define NNODES 10000
#define NEDGES 50000
#define CH 64
#define NSTAGES 65     // 64 i-stages + 1 bias stage

typedef _Float16 f16;
typedef f16 f16x8 __attribute__((ext_vector_type(8)));
typedef float f32x4 __attribute__((ext_vector_type(4)));

// Pack nn_w [64][4096] + nn_b [4096] into fragment-major Bp:
// Bp byte offset ((s*8 + tn*2 + h)*64 + ln)*16 holds 8 f16:
//   col = tn*16 + (ln&15), koff = h*32 + (ln>>4)*8 + j
//   s<64:  v = nn_w[koff_j*4096 + s*64 + col]   (kk = s*64+koff)
//   s==64: v = nn_b[koff_j*64 + col]            (bias rows, A=xj)
__global__ void pack_b_kernel(const float* __restrict__ nn_w,
                              const float* __restrict__ nn_b,
                              f16* __restrict__ Bp) {
    int idx = blockIdx.x * 256 + threadIdx.x;   // one 8-elem fragment row each
    if (idx >= NSTAGES * 512) return;           // 65*8*64 = 33280
    int ln = idx & 63;
    int h  = (idx >> 6) & 1;
    int tn = (idx >> 7) & 3;
    int s  = idx >> 9;
    int col  = tn * 16 + (ln & 15);
    int koff = h * 32 + (ln >> 4) * 8;
    f16x8 o;
#pragma unroll
    for (int j = 0; j < 8; ++j) {
        float v = (s < 64) ? nn_w[(koff + j) * 4096 + s * 64 + col]
                           : nn_b[(koff + j) * 64 + col];
        o[j] = (f16)v;
    }
    *(f16x8*)(Bp + (size_t)idx * 8) = o;
}

// out[n][o] = bias[o] + sum_k act(x[n][k]) * lw[k][o]
template<bool RELU_IN>
__global__ void root_linear_kernel(const float* __restrict__ x,
                                   const float* __restrict__ lw,
                                   const float* __restrict__ bias,
                                   float* __restrict__ out) {
    int idx = blockIdx.x * 256 + threadIdx.x;
    if (idx >= NNODES * CH) return;
    int n = idx >> 6;
    int o = idx & 63;
    const float* xr = x + n * CH;
    float acc = bias[o];
#pragma unroll
    for (int k = 0; k < CH; ++k) {
        float xv = xr[k];
        if (RELU_IN) xv = fmaxf(xv, 0.f);
        acc = fmaf(xv, lw[k * CH + o], acc);
    }
    out[idx] = acc;
}

// Edge GEMM: 128 edges/block, 4 waves (wave = 32 edges x 64 cols).
// blockIdx.y=0 -> stages 0..31, y=1 -> stages 32..63 + bias stage.
// B fragments stream from global (fragment-major, coalesced) into a register
// double-buffer; ea fragments live in registers; only xj in LDS. No K-loop
// barriers. Partial sums scatter via atomicAdd over dst.
template<bool RELU_IN>
__global__ __launch_bounds__(256)
void edge_gemm_kernel(const float* __restrict__ x,
                      const int* __restrict__ ei,   // [2][E]: src then dst
                      const float* __restrict__ ea, // [E][64] f32
                      const f16* __restrict__ Bp,   // fragment-major
                      float* __restrict__ out) {    // [N][64], atomicAdd
    __shared__ f16 xjS[128][66];   // [edge_local][i], row 132B (33 dwords, odd)

    int t  = threadIdx.x;
    int e0 = blockIdx.x * 128;

    // Gather x[src[e]] rows (fused ReLU) into LDS, f16, b32 writes.
    // 128 edges x 32 float2 = 4096 items / 256 thr = 16 iters.
    for (int v = 0; v < 128 * 32; v += 256) {
        int idx = v + t;
        int el = idx >> 5;          // edge_local
        int ip = idx & 31;          // float2 index within row
        int e  = e0 + el;
        float x0 = 0.f, x1 = 0.f;
        if (e < NEDGES) {
            int srow = ei[e];       // src
            const float* xr = x + srow * CH + ip * 2;
            x0 = xr[0]; x1 = xr[1];
            if (RELU_IN) { x0 = fmaxf(x0, 0.f); x1 = fmaxf(x1, 0.f); }
        }
        union { f16 h[2]; unsigned u; } pk;
        pk.h[0] = (f16)x0; pk.h[1] = (f16)x1;
        *(unsigned*)&xjS[el][ip * 2] = pk.u;
    }

    int wv  = t >> 6;       // wave 0..3
    int ln  = t & 63;
    int l15 = ln & 15;
    int l4  = ln >> 4;
    int er0 = wv * 32;

    // ea fragments (stage-invariant): eav[ab][h] = ea[e][h*32+l4*8 .. +8]
    f16x8 eav[2][2];
#pragma unroll
    for (int ab = 0; ab < 2; ++ab) {
        int e = e0 + er0 + ab * 16 + l15;
#pragma unroll
        for (int h = 0; h < 2; ++h) {
            float4 u0 = {0.f, 0.f, 0.f, 0.f}, u1 = {0.f, 0.f, 0.f, 0.f};
            if (e < NEDGES) {
                const float4* p = (const float4*)(ea + e * CH + h * 32 + l4 * 8);
                u0 = p[0]; u1 = p[1];
            }
            f16x8 f;
            f[0]=(f16)u0.x; f[1]=(f16)u0.y; f[2]=(f16)u0.z; f[3]=(f16)u0.w;
            f[4]=(f16)u1.x; f[5]=(f16)u1.y; f[6]=(f16)u1.z; f[7]=(f16)u1.w;
            eav[ab][h] = f;
        }
    }

    f32x4 acc[2][4];
#pragma unroll
    for (int ms = 0; ms < 2; ++ms)
#pragma unroll
        for (int tn = 0; tn < 4; ++tn)
            acc[ms][tn] = (f32x4){0.f, 0.f, 0.f, 0.f};

    const char* bB = (const char*)Bp + ln * 16;
    int sb = blockIdx.y * 32;

#define LOAD_B(dst, sidx) do { \
        const char* _p = bB + (size_t)(sidx) * 8192; \
        _Pragma("unroll") \
        for (int q = 0; q < 8; ++q) dst[q] = *(const f16x8*)(_p + q * 1024); \
    } while (0)

#define COMPUTE(sidx, bf) do { \
        f16 _xa = xjS[er0 + l15][(sidx)]; \
        f16 _xb = xjS[er0 + 16 + l15][(sidx)]; \
        f16x8 _xav = {_xa,_xa,_xa,_xa,_xa,_xa,_xa,_xa}; \
        f16x8 _xbv = {_xb,_xb,_xb,_xb,_xb,_xb,_xb,_xb}; \
        _Pragma("unroll") \
        for (int h = 0; h < 2; ++h) { \
            f16x8 _afa = eav[0][h] * _xav; \
            f16x8 _afb = eav[1][h] * _xbv; \
            _Pragma("unroll") \
            for (int tn = 0; tn < 4; ++tn) { \
                acc[0][tn] = __builtin_amdgcn_mfma_f32_16x16x32_f16(_afa, bf[tn*2+h], acc[0][tn], 0, 0, 0); \
                acc[1][tn] = __builtin_amdgcn_mfma_f32_16x16x32_f16(_afb, bf[tn*2+h], acc[1][tn], 0, 0, 0); \
            } \
        } \
    } while (0)

    __syncthreads();   // xjS ready; only barrier in the kernel

    f16x8 bA[8], bB_[8];
    LOAD_B(bA, sb);
#pragma unroll 1
    for (int s2 = 0; s2 < 16; ++s2) {
        int s = sb + s2 * 2;
        LOAD_B(bB_, s + 1);
        COMPUTE(s, bA);
        LOAD_B(bA, s + 2);          // last iter: y0 loads s=32 (harmless), y1 loads s=64 (bias frags)
        COMPUTE(s + 1, bB_);
    }

    if (blockIdx.y == 1) {
        // bias stage: A[e][i] = xj[e][i]; B frags already in bA (s=64)
#pragma unroll
        for (int h = 0; h < 2; ++h) {
            f16x8 afa = *(const f16x8*)&xjS[er0 + l15][h * 32 + l4 * 8];
            f16x8 afb = *(const f16x8*)&xjS[er0 + 16 + l15][h * 32 + l4 * 8];
#pragma unroll
            for (int tn = 0; tn < 4; ++tn) {
                acc[0][tn] = __builtin_amdgcn_mfma_f32_16x16x32_f16(afa, bA[tn*2+h], acc[0][tn], 0, 0, 0);
                acc[1][tn] = __builtin_amdgcn_mfma_f32_16x16x32_f16(afb, bA[tn*2+h], acc[1][tn], 0, 0, 0);
            }
        }
    }

    // Scatter: D lane map: col = lane&15, row = (lane>>4)*4 + reg.
#pragma unroll
    for (int ms = 0; ms < 2; ++ms) {
#pragma unroll
        for (int q = 0; q < 4; ++q) {
            int el = er0 + ms * 16 + l4 * 4 + q;
            int e  = e0 + el;
            if (e < NEDGES) {
                int drow = ei[NEDGES + e];    // dst
                float* orow = out + drow * CH;
#pragma unroll
                for (int tn = 0; tn < 4; ++tn) {
                    atomicAdd(orow + tn * 16 + l15, acc[ms][tn][q]);
                }
            }
        }
    }
#undef LOAD_B
#undef COMPUTE
}

extern "C" void kernel_launch(void* const* d_in, const int* in_sizes, int n_in,
                              void* d_out, int out_size, void* d_ws, size_t ws_size,
                              hipStream_t stream) {
    const float* feature = (const float*)d_in[0];
    const int*   ei      = (const int*)d_in[1];
    const float* ea      = (const float*)d_in[2];
    const float* nn_w0   = (const float*)d_in[3];
    const float* nn_b0   = (const float*)d_in[4];
    const float* lin_w0  = (const float*)d_in[5];
    const float* bias0   = (const float*)d_in[6];
    const float* nn_w1   = (const float*)d_in[7];
    const float* nn_b1   = (const float*)d_in[8];
    const float* lin_w1  = (const float*)d_in[9];
    const float* bias1   = (const float*)d_in[10];
    const float* fin_w   = (const float*)d_in[11];
    const float* fin_b   = (const float*)d_in[12];
    float* out = (float*)d_out;

    char* ws = (char*)d_ws;
    float* buf0 = (float*)ws;                        // 2,560,000 B
    float* buf1 = (float*)(ws + 2560000);            // 2,560,000 B
    f16* Bp0 = (f16*)(ws + 5120000);                 // 532,480 B
    f16* Bp1 = (f16*)(ws + 5120000 + 532480);        // 532,480 B

    int pack_blocks = (NSTAGES * 512 + 255) / 256;   // 130
    pack_b_kernel<<<pack_blocks, 256, 0, stream>>>(nn_w0, nn_b0, Bp0);
    pack_b_kernel<<<pack_blocks, 256, 0, stream>>>(nn_w1, nn_b1, Bp1);

    dim3 rg((NNODES * CH + 255) / 256);
    dim3 eg((NEDGES + 127) / 128, 2);

    // layer 0
    root_linear_kernel<false><<<rg, 256, 0, stream>>>(feature, lin_w0, bias0, buf0);
    edge_gemm_kernel<false><<<eg, 256, 0, stream>>>(feature, ei, ea, Bp0, buf0);
    // layer 1 (ReLU fused into loads)
    root_linear_kernel<true><<<rg, 256, 0, stream>>>(buf0, lin_w1, bias1, buf1);
    edge_gemm_kernel<true><<<eg, 256, 0, stream>>>(buf0, ei, ea, Bp1, buf1);
    // final linear (ReLU fused)
    root_linear_kernel<true><<<rg, 256, 0, stream>>>(buf1, fin_w, fin_b, out);
}